// Round 10
// baseline (209.641 us; speedup 1.0000x reference)
//
#include <hip/hip_runtime.h>
#include <hip/hip_bf16.h>
#include <stdint.h>

typedef unsigned short u16;
typedef __bf16 bf16x8 __attribute__((ext_vector_type(8)));
typedef float f32x4 __attribute__((ext_vector_type(4)));
typedef float f32x16 __attribute__((ext_vector_type(16)));
typedef unsigned short us8 __attribute__((ext_vector_type(8)));

__device__ __forceinline__ u16 f2bf(float f) {
  union { float f; uint32_t u; } v; v.f = f;
  uint32_t u = v.u;
  return (u16)((u + 0x7FFFu + ((u >> 16) & 1u)) >> 16);
}

__device__ __forceinline__ uint32_t cvtpk(float a, float b) {
  uint32_t r;
  asm("v_cvt_pk_bf16_f32 %0, %1, %2" : "=v"(r) : "v"(a), "v"(b));
  return r;
}

__device__ __forceinline__ void gload_lds16(const void* g, void* l) {
  __builtin_amdgcn_global_load_lds(
      (const __attribute__((address_space(1))) void*)(uintptr_t)g,
      (__attribute__((address_space(3))) void*)(uint32_t)(uintptr_t)l,
      16, 0, 0);
}

__device__ __forceinline__ float vsum16(f32x16 v) {
  float a = (v[0] + v[1]) + (v[2] + v[3]);
  float b = (v[4] + v[5]) + (v[6] + v[7]);
  float c = (v[8] + v[9]) + (v[10] + v[11]);
  float d = (v[12] + v[13]) + (v[14] + v[15]);
  return (a + b) + (c + d);
}

#define CROW(r, g) (((r) & 3) + 8 * ((r) >> 2) + 4 * (g))

// ---------------- weight conversions only (x/enc cvt fused into qkv GEMM) ------
// blocks [0,768): Wq/Wk/Wv transpose | [768,1024): Wo transpose
__global__ __launch_bounds__(256) void cvt_w_k(
    const float* __restrict__ Wq, const float* __restrict__ Wk,
    const float* __restrict__ Wv, const float* __restrict__ Wo,
    u16* __restrict__ wqb, u16* __restrict__ wkb,
    u16* __restrict__ wvb, u16* __restrict__ wob) {
  __shared__ float t[64][65];
  const int blk = blockIdx.x;
  const int tid = threadIdx.x;

  if (blk < 768) {
    int z = blk >> 8;
    const float* W = (z == 0) ? Wq : (z == 1) ? Wk : Wv;
    u16* o = (z == 0) ? wqb : (z == 1) ? wkb : wvb;
    const int r = blk & 255;
    const int h = r >> 4, d0 = (r & 15) * 64;
    const float* Wb = W + ((size_t)h << 16) + (size_t)d0 * 64;
#pragma unroll
    for (int i = 0; i < 4; ++i) {
      int idx = tid + i * 256;
      int dl = idx >> 4, e4 = (idx & 15) << 2;
      float4 v = *(const float4*)(Wb + dl * 64 + e4);
      t[dl][e4 + 0] = v.x; t[dl][e4 + 1] = v.y; t[dl][e4 + 2] = v.z; t[dl][e4 + 3] = v.w;
    }
    __syncthreads();
#pragma unroll
    for (int i = 0; i < 2; ++i) {
      int idx = tid + i * 256;
      int e = idx >> 3, dc = (idx & 7) * 8;
      us8 w;
#pragma unroll
      for (int j = 0; j < 8; ++j) w[j] = f2bf(t[dc + j][e]);
      *(us8*)(o + ((size_t)(h * 64 + e)) * 1024 + d0 + dc) = w;
    }
    return;
  }

  {
    int r = blk - 768;
    const int k0 = (r & 15) * 64, n0 = (r >> 4) * 64;
    const float* Wb = Wo + (size_t)k0 * 1024 + n0;
#pragma unroll
    for (int i = 0; i < 4; ++i) {
      int idx = tid + i * 256;
      int kl = idx >> 4, n4 = (idx & 15) << 2;
      float4 v = *(const float4*)(Wb + (size_t)kl * 1024 + n4);
      t[kl][n4 + 0] = v.x; t[kl][n4 + 1] = v.y; t[kl][n4 + 2] = v.z; t[kl][n4 + 3] = v.w;
    }
    __syncthreads();
#pragma unroll
    for (int i = 0; i < 2; ++i) {
      int idx = tid + i * 256;
      int n = idx >> 3, kc = (idx & 7) * 8;
      us8 w;
#pragma unroll
      for (int j = 0; j < 8; ++j) w[j] = f2bf(t[kc + j][n]);
      *(us8*)(wob + ((size_t)(n0 + n)) * 1024 + k0 + kc) = w;
    }
  }
}

// ---------------- GEMM mainloop, bf16 A+B (128x128, BK=32, 2-deep vmcnt(4)) ----
__device__ __forceinline__ void gemm_core(const char* Ac, const char* Bc, int K,
                                          int m0, int n0, int tid,
                                          char* As0, char* As1, char* Bs0, char* Bs1,
                                          f32x4 (&acc)[4][4]) {
  const int wave = tid >> 6, lane = tid & 63;
  const int lo = lane & 15, hi = lane >> 4;
  const int wr = wave >> 1, wc = wave & 1;
  const int o0 = wave * 1024 + lane * 16;
  const int r0 = o0 >> 6, cb0 = o0 & 63;
  const int o1 = o0 + 4096;
  const int r1 = o1 >> 6, cb1 = o1 & 63;
  const size_t ksz = (size_t)K * 2;

  auto STAGE = [&](int t) {
    const size_t kb = (size_t)t * 64;
    char* Ad = (t & 1) ? As1 : As0;
    char* Bd = (t & 1) ? Bs1 : Bs0;
    gload_lds16(Ac + (size_t)(m0 + r0) * ksz + kb + cb0, Ad + o0);
    gload_lds16(Ac + (size_t)(m0 + r1) * ksz + kb + cb1, Ad + o1);
    gload_lds16(Bc + (size_t)(n0 + r0) * ksz + kb + cb0, Bd + o0);
    gload_lds16(Bc + (size_t)(n0 + r1) * ksz + kb + cb1, Bd + o1);
  };

  const int NK = K >> 5;
  STAGE(0);
  STAGE(1);

  for (int kk = 0; kk < NK; ++kk) {
    if (kk < NK - 1) {
      asm volatile("s_waitcnt vmcnt(4)" ::: "memory");
    } else {
      asm volatile("s_waitcnt vmcnt(0)" ::: "memory");
    }
    __builtin_amdgcn_s_barrier();
    __builtin_amdgcn_sched_barrier(0);
    const u16* Asb = (const u16*)((kk & 1) ? As1 : As0);
    const u16* Bsb = (const u16*)((kk & 1) ? Bs1 : Bs0);
    bf16x8 af[4], bfr[4];
#pragma unroll
    for (int i = 0; i < 4; ++i) {
      af[i]  = *(const bf16x8*)(Asb + (wr * 64 + i * 16 + lo) * 32 + hi * 8);
      bfr[i] = *(const bf16x8*)(Bsb + (wc * 64 + i * 16 + lo) * 32 + hi * 8);
    }
    asm volatile("s_waitcnt lgkmcnt(0)" ::: "memory");
    __builtin_amdgcn_sched_barrier(0);
    __builtin_amdgcn_s_barrier();
    if (kk + 2 < NK) STAGE(kk + 2);
    __builtin_amdgcn_s_setprio(1);
#pragma unroll
    for (int am = 0; am < 4; ++am)
#pragma unroll
      for (int bn = 0; bn < 4; ++bn)
        acc[am][bn] = __builtin_amdgcn_mfma_f32_16x16x32_bf16(af[am], bfr[bn], acc[am][bn], 0, 0, 0);
    __builtin_amdgcn_s_setprio(0);
  }
}

// ---------------- GEMM mainloop, f32 A (fused convert) + bf16 B ----------------
// A staged as f32 [128][32] (128B rows, 16KB/buf), source-col pre-swizzled by
// ((lane>>3)<<4) so fragment reads (col ^ ((lo&7)<<4)) are 2-way conflict-free.
// 6 loads/STAGE -> counted wait is vmcnt(6). Fragments converted via cvtpk
// (bit-identical to f2bf path).
__device__ __forceinline__ void gemm_core_f32a(const float* Af, const char* Bc, int K,
                                               int m0, int n0, int tid,
                                               char* Afs0, char* Afs1, char* Bs0, char* Bs1,
                                               f32x4 (&acc)[4][4]) {
  const int wave = tid >> 6, lane = tid & 63;
  const int lo = lane & 15, hi = lane >> 4;
  const int wr = wave >> 1, wc = wave & 1;
  // A staging: instr j covers byte o = j*4096 + wave*1024 + lane*16 of 16KB buf
  const int ao = wave * 1024 + lane * 16;
  const int arow_base = (ao >> 7);               // wave*8 + (lane>>3)
  const int ascol = (ao & 127) ^ ((lane >> 3) << 4);  // pre-swizzled source col
  // B staging (bf16 [128][32], 8KB): 2 instrs
  const int o0 = wave * 1024 + lane * 16;
  const int r0 = o0 >> 6, cb0 = o0 & 63;
  const int o1 = o0 + 4096;
  const int r1 = o1 >> 6, cb1 = o1 & 63;
  const size_t kszB = (size_t)K * 2;
  const size_t kszA = (size_t)K * 4;

  auto STAGE = [&](int t) {
    char* Ad = (t & 1) ? Afs1 : Afs0;
    char* Bd = (t & 1) ? Bs1 : Bs0;
    const size_t kbA = (size_t)t * 128;  // 32 k * 4B
    const size_t kbB = (size_t)t * 64;   // 32 k * 2B
#pragma unroll
    for (int j = 0; j < 4; ++j) {
      gload_lds16((const char*)Af + (size_t)(m0 + arow_base + j * 32) * kszA + kbA + ascol,
                  Ad + j * 4096 + ao);
    }
    gload_lds16(Bc + (size_t)(n0 + r0) * kszB + kbB + cb0, Bd + o0);
    gload_lds16(Bc + (size_t)(n0 + r1) * kszB + kbB + cb1, Bd + o1);
  };

  const int NK = K >> 5;
  STAGE(0);
  STAGE(1);

  const int aswz = (lo & 7) << 4;  // read-side swizzle (row&7 == lo&7)

  for (int kk = 0; kk < NK; ++kk) {
    if (kk < NK - 1) {
      asm volatile("s_waitcnt vmcnt(6)" ::: "memory");
    } else {
      asm volatile("s_waitcnt vmcnt(0)" ::: "memory");
    }
    __builtin_amdgcn_s_barrier();
    __builtin_amdgcn_sched_barrier(0);
    const char* Asb = (kk & 1) ? Afs1 : Afs0;
    const u16* Bsb = (const u16*)((kk & 1) ? Bs1 : Bs0);
    bf16x8 af[4], bfr[4];
#pragma unroll
    for (int i = 0; i < 4; ++i) {
      const int row = wr * 64 + i * 16 + lo;
      f32x4 a0 = *(const f32x4*)(Asb + row * 128 + ((hi * 32) ^ aswz));
      f32x4 a1 = *(const f32x4*)(Asb + row * 128 + ((hi * 32 + 16) ^ aswz));
      union { uint32_t u[4]; bf16x8 v; } cv;
      cv.u[0] = cvtpk(a0[0], a0[1]);
      cv.u[1] = cvtpk(a0[2], a0[3]);
      cv.u[2] = cvtpk(a1[0], a1[1]);
      cv.u[3] = cvtpk(a1[2], a1[3]);
      af[i] = cv.v;
      bfr[i] = *(const bf16x8*)(Bsb + (wc * 64 + i * 16 + lo) * 32 + hi * 8);
    }
    asm volatile("s_waitcnt lgkmcnt(0)" ::: "memory");
    __builtin_amdgcn_sched_barrier(0);
    __builtin_amdgcn_s_barrier();
    if (kk + 2 < NK) STAGE(kk + 2);
    __builtin_amdgcn_s_setprio(1);
#pragma unroll
    for (int am = 0; am < 4; ++am)
#pragma unroll
      for (int bn = 0; bn < 4; ++bn)
        acc[am][bn] = __builtin_amdgcn_mfma_f32_16x16x32_bf16(af[am], bfr[bn], acc[am][bn], 0, 0, 0);
    __builtin_amdgcn_s_setprio(0);
  }
}

// ---------------- fused Q + KV projections (f32 A, fused convert) ----------
__global__ __launch_bounds__(256) void qkv_proj_k(
    const float* __restrict__ x, const float* __restrict__ enc,
    const u16* __restrict__ wqb, const u16* __restrict__ wkvb,
    const float* __restrict__ bq, const float* __restrict__ bk_,
    const float* __restrict__ bv_,
    u16* __restrict__ Qg, u16* __restrict__ Kg, u16* __restrict__ Vt, float scale) {
  __shared__ __attribute__((aligned(16))) char As[2][16384];
  __shared__ __attribute__((aligned(16))) char Bs[2][8192];
  const int blk = blockIdx.x;
  const int tid = threadIdx.x;
  const int wave = tid >> 6, lane = tid & 63;
  const int lo = lane & 15, hi = lane >> 4;
  const int wr = wave >> 1, wc = wave & 1;

  f32x4 acc[4][4] = {};

  if (blk < 512) {
    const int n0 = (blk & 7) * 128, m0 = (blk >> 3) * 128;
    gemm_core_f32a(x, (const char*)wqb, 1024, m0, n0, tid,
                   As[0], As[1], Bs[0], Bs[1], acc);
#pragma unroll
    for (int bn = 0; bn < 4; ++bn) {
      int col = n0 + wc * 64 + bn * 16 + lo;
      float bb = bq[col];
      int hh = col >> 6, e = col & 63;
#pragma unroll
      for (int am = 0; am < 4; ++am) {
#pragma unroll
        for (int r = 0; r < 4; ++r) {
          int row = m0 + wr * 64 + am * 16 + hi * 4 + r;
          int b = row >> 11, s = row & 2047;
          Qg[(((size_t)(b * 16 + hh) * 2048 + s) << 6) + e] = f2bf((acc[am][bn][r] + bb) * scale);
        }
      }
    }
  } else {
    const int r_ = blk - 512;
    const int n0 = (r_ & 15) * 128, m0 = (r_ >> 4) * 128;
    gemm_core_f32a(enc, (const char*)wkvb, 1024, m0, n0, tid,
                   As[0], As[1], Bs[0], Bs[1], acc);
    const bool isV = (n0 + wc * 64) >= 1024;  // wave-uniform
    if (!isV) {
#pragma unroll
      for (int bn = 0; bn < 4; ++bn) {
        int col = n0 + wc * 64 + bn * 16 + lo;
        float bb = bk_[col];
        int hh = col >> 6, e = col & 63;
#pragma unroll
        for (int am = 0; am < 4; ++am) {
#pragma unroll
          for (int r = 0; r < 4; ++r) {
            int row = m0 + wr * 64 + am * 16 + hi * 4 + r;
            int b = row >> 11, s = row & 2047;
            s = (s & ~12) | ((s & 4) << 1) | ((s & 8) >> 1);
            Kg[(((size_t)(b * 16 + hh) * 2048 + s) << 6) + e] = f2bf(acc[am][bn][r] + bb);
          }
        }
      }
    } else {
#pragma unroll
      for (int bn = 0; bn < 4; ++bn) {
        int c = (n0 + wc * 64 + bn * 16 + lo) - 1024;
        float bb = bv_[c];
        int hh = c >> 6, e = c & 63;
#pragma unroll
        for (int am = 0; am < 4; ++am) {
          int row = m0 + wr * 64 + am * 16 + hi * 4;
          int b = row >> 11, s = row & 2047;
          uint2 wv;
          wv.x = cvtpk(acc[am][bn][0] + bb, acc[am][bn][1] + bb);
          wv.y = cvtpk(acc[am][bn][2] + bb, acc[am][bn][3] + bb);
          *(uint2*)(Vt + (((size_t)(b * 16 + hh) * 64 + e) * 2048 + s)) = wv;
        }
      }
    }
  }
}

// ---------------- output projection (bf16 A from attn) ----------------
__global__ __launch_bounds__(256) void out_proj_k(const u16* __restrict__ A,
                                                  const u16* __restrict__ B,
                                                  const float* __restrict__ bias,
                                                  float* __restrict__ C, int M, int N, int K) {
  __shared__ __attribute__((aligned(16))) char As[2][8192];
  __shared__ __attribute__((aligned(16))) char Bs[2][8192];
  const int tid = threadIdx.x;
  const int wave = tid >> 6, lane = tid & 63;
  const int lo = lane & 15, hi = lane >> 4;
  const int wr = wave >> 1, wc = wave & 1;
  const int n0 = blockIdx.x * 128, m0 = blockIdx.y * 128;

  f32x4 acc[4][4] = {};
  gemm_core((const char*)A, (const char*)B, K, m0, n0, tid,
            As[0], As[1], Bs[0], Bs[1], acc);

#pragma unroll
  for (int bn = 0; bn < 4; ++bn) {
    int col = n0 + wc * 64 + bn * 16 + lo;
    float bb = bias[col];
#pragma unroll
    for (int am = 0; am < 4; ++am) {
#pragma unroll
      for (int r = 0; r < 4; ++r) {
        int row = m0 + wr * 64 + am * 16 + hi * 4 + r;
        C[(size_t)row * N + col] = acc[am][bn][r] + bb;
      }
    }
  }
}

// ---------------- flash attention (R4-proven body, VALU row-sum) ----------------
// Q pre-scaled by log2(e)/8 in its projection. exp2 accumulated raw; normalize at end.
__global__ __launch_bounds__(256, 4) void attn_k(const u16* __restrict__ Qg,
                                                 const u16* __restrict__ Kg,
                                                 const u16* __restrict__ Vtg,
                                                 u16* __restrict__ Hd) {
  const int W = blockIdx.x;
  const int bid = (W >> 7) * 128 + (W & 7) * 16 + ((W >> 3) & 15);
  const int bh = bid >> 4;
  const int q0 = (bid & 15) * 128;
  const int tid = threadIdx.x;
  const int w = tid >> 6, lane = tid & 63;
  const int q31 = lane & 31, g = lane >> 5;

  __shared__ __attribute__((aligned(16))) char LB[2][16384];  // [K 8KB | V 8KB] x2

  bf16x8 qf0, qf1, qf2, qf3;
  {
    const char* Qrow = (const char*)(Qg + ((size_t)bh * 2048 + q0 + w * 32 + q31) * 64) + g * 16;
    qf0 = *(const bf16x8*)(Qrow);
    qf1 = *(const bf16x8*)(Qrow + 32);
    qf2 = *(const bf16x8*)(Qrow + 64);
    qf3 = *(const bf16x8*)(Qrow + 96);
  }

  f32x16 acc0 = {}, acc1 = {};
  float lrun = 0.f;

  const int lrow = lane >> 3;
  const int scol = ((lane & 7) ^ lrow) << 4;
  const char* kp = (const char*)Kg + (size_t)bh * 262144 + (size_t)(w * 16 + lrow) * 128 + scol;
  const char* vp = (const char*)Vtg + (size_t)bh * 262144 + (size_t)(w * 16 + lrow) * 4096 + scol;

  auto STAGE = [&](int c) {
    char* kb = &LB[c][0] + w * 2048;
    char* vb = kb + 8192;
    gload_lds16(kp, kb);
    gload_lds16(kp + 1024, kb + 1024);
    gload_lds16(vp, vb);
    gload_lds16(vp + 32768, vb + 1024);
    kp += 8192;
    vp += 128;
  };

  STAGE(0);

  const int swz = (q31 & 7) << 4;
  const int krow = q31 * 128;
  const int ko0 = (g * 16) ^ swz;
  const int ko1 = (32 + g * 16) ^ swz;
  const int ko2 = (64 + g * 16) ^ swz;
  const int ko3 = (96 + g * 16) ^ swz;

  int cur = 0;
  for (int t = 0; t < 32; ++t) {
    asm volatile("s_waitcnt vmcnt(0)" ::: "memory");
    __builtin_amdgcn_s_barrier();
    asm volatile("" ::: "memory");
    if (t < 31) STAGE(cur ^ 1);

    const char* Kc = &LB[cur][0];
    const char* Vc = Kc + 8192;

    f32x16 p0 = {}, p1 = {};
    __builtin_amdgcn_s_setprio(1);
    {
      bf16x8 kf;
      kf = *(const bf16x8*)(Kc + krow + ko0);
      p0 = __builtin_amdgcn_mfma_f32_32x32x16_bf16(kf, qf0, p0, 0, 0, 0);
      kf = *(const bf16x8*)(Kc + 4096 + krow + ko0);
      p1 = __builtin_amdgcn_mfma_f32_32x32x16_bf16(kf, qf0, p1, 0, 0, 0);
      kf = *(const bf16x8*)(Kc + krow + ko1);
      p0 = __builtin_amdgcn_mfma_f32_32x32x16_bf16(kf, qf1, p0, 0, 0, 0);
      kf = *(const bf16x8*)(Kc + 4096 + krow + ko1);
      p1 = __builtin_amdgcn_mfma_f32_32x32x16_bf16(kf, qf1, p1, 0, 0, 0);
      kf = *(const bf16x8*)(Kc + krow + ko2);
      p0 = __builtin_amdgcn_mfma_f32_32x32x16_bf16(kf, qf2, p0, 0, 0, 0);
      kf = *(const bf16x8*)(Kc + 4096 + krow + ko2);
      p1 = __builtin_amdgcn_mfma_f32_32x32x16_bf16(kf, qf2, p1, 0, 0, 0);
      kf = *(const bf16x8*)(Kc + krow + ko3);
      p0 = __builtin_amdgcn_mfma_f32_32x32x16_bf16(kf, qf3, p0, 0, 0, 0);
      kf = *(const bf16x8*)(Kc + 4096 + krow + ko3);
      p1 = __builtin_amdgcn_mfma_f32_32x32x16_bf16(kf, qf3, p1, 0, 0, 0);
    }
    __builtin_amdgcn_s_setprio(0);

#pragma unroll
    for (int i = 0; i < 16; ++i) p0[i] = __builtin_amdgcn_exp2f(p0[i]);
#pragma unroll
    for (int i = 0; i < 16; ++i) p1[i] = __builtin_amdgcn_exp2f(p1[i]);

    float rs = vsum16(p0) + vsum16(p1);
    {
      float ra = rs, rb = rs;
      asm("v_permlane32_swap_b32 %0, %1" : "+v"(ra), "+v"(rb));
      rs += g ? ra : rb;
    }
    lrun += rs;

    union PU { uint32_t u[4]; bf16x8 v; } a0, a1, a2, a3;
    a0.u[0] = cvtpk(p0[0], p0[1]);   a0.u[1] = cvtpk(p0[2], p0[3]);
    a0.u[2] = cvtpk(p0[4], p0[5]);   a0.u[3] = cvtpk(p0[6], p0[7]);
    a1.u[0] = cvtpk(p0[8], p0[9]);   a1.u[1] = cvtpk(p0[10], p0[11]);
    a1.u[2] = cvtpk(p0[12], p0[13]); a1.u[3] = cvtpk(p0[14], p0[15]);
    a2.u[0] = cvtpk(p1[0], p1[1]);   a2.u[1] = cvtpk(p1[2], p1[3]);
    a2.u[2] = cvtpk(p1[4], p1[5]);   a2.u[3] = cvtpk(p1[6], p1[7]);
    a3.u[0] = cvtpk(p1[8], p1[9]);   a3.u[1] = cvtpk(p1[10], p1[11]);
    a3.u[2] = cvtpk(p1[12], p1[13]); a3.u[3] = cvtpk(p1[14], p1[15]);

    __builtin_amdgcn_s_setprio(1);
    {
      bf16x8 vf;
      vf = *(const bf16x8*)(Vc + krow + ko0);
      acc0 = __builtin_amdgcn_mfma_f32_32x32x16_bf16(a0.v, vf, acc0, 0, 0, 0);
      vf = *(const bf16x8*)(Vc + 4096 + krow + ko0);
      acc1 = __builtin_amdgcn_mfma_f32_32x32x16_bf16(a0.v, vf, acc1, 0, 0, 0);
      vf = *(const bf16x8*)(Vc + krow + ko1);
      acc0 = __builtin_amdgcn_mfma_f32_32x32x16_bf16(a1.v, vf, acc0, 0, 0, 0);
      vf = *(const bf16x8*)(Vc + 4096 + krow + ko1);
      acc1 = __builtin_amdgcn_mfma_f32_32x32x16_bf16(a1.v, vf, acc1, 0, 0, 0);
      vf = *(const bf16x8*)(Vc + krow + ko2);
      acc0 = __builtin_amdgcn_mfma_f32_32x32x16_bf16(a2.v, vf, acc0, 0, 0, 0);
      vf = *(const bf16x8*)(Vc + 4096 + krow + ko2);
      acc1 = __builtin_amdgcn_mfma_f32_32x32x16_bf16(a2.v, vf, acc1, 0, 0, 0);
      vf = *(const bf16x8*)(Vc + krow + ko3);
      acc0 = __builtin_amdgcn_mfma_f32_32x32x16_bf16(a3.v, vf, acc0, 0, 0, 0);
      vf = *(const bf16x8*)(Vc + 4096 + krow + ko3);
      acc1 = __builtin_amdgcn_mfma_f32_32x32x16_bf16(a3.v, vf, acc1, 0, 0, 0);
    }
    __builtin_amdgcn_s_setprio(0);

    cur ^= 1;
  }

  float linv = 1.f / lrun;
  const int b = bh >> 4, h = bh & 15;
  u16* Ho = Hd + ((size_t)b * 2048 + q0 + w * 32) * 1024 + h * 64;
#pragma unroll
  for (int r = 0; r < 16; ++r) {
    float iv = __shfl(linv, CROW(r, g));
    int q = CROW(r, g);
    u16* row = Ho + (size_t)q * 1024;
    row[q31]      = f2bf(acc0[r] * iv);
    row[32 + q31] = f2bf(acc1[r] * iv);
  }
}

// ---------------- launch ----------------

extern "C" void kernel_launch(void* const* d_in, const int* in_sizes, int n_in,
                              void* d_out, int out_size, void* d_ws, size_t ws_size,
                              hipStream_t stream) {
  const float* x   = (const float*)d_in[0];
  const float* enc = (const float*)d_in[1];
  const float* Wq  = (const float*)d_in[2];
  const float* bq  = (const float*)d_in[3];
  const float* Wk  = (const float*)d_in[4];
  const float* bk  = (const float*)d_in[5];
  const float* Wv  = (const float*)d_in[6];
  const float* bv  = (const float*)d_in[7];
  const float* Wo  = (const float*)d_in[8];
  const float* bo  = (const float*)d_in[9];
  float* out = (float*)d_out;
  char* ws = (char*)d_ws;

  const size_t SZ = 16u * 1024u * 1024u;
  u16* hd  = (u16*)(ws + 0 * SZ);
  u16* Qg  = (u16*)(ws + 2 * SZ);
  u16* Kg  = (u16*)(ws + 3 * SZ);
  u16* vtb = (u16*)(ws + 4 * SZ);  // Vt [B,H,64,S], written directly by KV gemm
  u16* wqb = (u16*)(ws + 5 * SZ + 0u * (2u << 20));
  u16* wkb = (u16*)(ws + 5 * SZ + 1u * (2u << 20));  // wkb+wvb contiguous [2048][1024]
  u16* wvb = (u16*)(ws + 5 * SZ + 2u * (2u << 20));
  u16* wob = (u16*)(ws + 5 * SZ + 3u * (2u << 20));

  const float cs = 0.18033688011112042f;  // log2(e)/8, folded into Q projection

  cvt_w_k<<<1024, 256, 0, stream>>>(Wq, Wk, Wv, Wo, wqb, wkb, wvb, wob);

  qkv_proj_k<<<1536, 256, 0, stream>>>(x, enc, wqb, wkb, bq, bk, bv, Qg, Kg, vtb, cs);

  attn_k<<<1024, 256, 0, stream>>>(Qg, Kg, vtb, hd);

  out_proj_k<<<dim3(8, 64), 256, 0, stream>>>(hd, wob, bo, out, 8192, 1024, 1024);
}

// Round 11
// 192.739 us; speedup vs baseline: 1.0877x; 1.0877x over previous
//
#include <hip/hip_runtime.h>
#include <hip/hip_bf16.h>
#include <stdint.h>

typedef unsigned short u16;
typedef __bf16 bf16x8 __attribute__((ext_vector_type(8)));
typedef float f32x4 __attribute__((ext_vector_type(4)));
typedef float f32x16 __attribute__((ext_vector_type(16)));
typedef unsigned short us8 __attribute__((ext_vector_type(8)));

__device__ __forceinline__ u16 f2bf(float f) {
  union { float f; uint32_t u; } v; v.f = f;
  uint32_t u = v.u;
  return (u16)((u + 0x7FFFu + ((u >> 16) & 1u)) >> 16);
}

__device__ __forceinline__ uint32_t cvtpk(float a, float b) {
  uint32_t r;
  asm("v_cvt_pk_bf16_f32 %0, %1, %2" : "=v"(r) : "v"(a), "v"(b));
  return r;
}

__device__ __forceinline__ void gload_lds16(const void* g, void* l) {
  __builtin_amdgcn_global_load_lds(
      (const __attribute__((address_space(1))) void*)(uintptr_t)g,
      (__attribute__((address_space(3))) void*)(uint32_t)(uintptr_t)l,
      16, 0, 0);
}

__device__ __forceinline__ float vsum16(f32x16 v) {
  float a = (v[0] + v[1]) + (v[2] + v[3]);
  float b = (v[4] + v[5]) + (v[6] + v[7]);
  float c = (v[8] + v[9]) + (v[10] + v[11]);
  float d = (v[12] + v[13]) + (v[14] + v[15]);
  return (a + b) + (c + d);
}

#define CROW(r, g) (((r) & 3) + 8 * ((r) >> 2) + 4 * (g))

// ---------------- merged conversions ----------------
__global__ __launch_bounds__(256) void cvt_all_k(
    const float* __restrict__ x, const float* __restrict__ enc,
    const float* __restrict__ Wq, const float* __restrict__ Wk,
    const float* __restrict__ Wv, const float* __restrict__ Wo,
    u16* __restrict__ xb, u16* __restrict__ eb,
    u16* __restrict__ wqb, u16* __restrict__ wkb,
    u16* __restrict__ wvb, u16* __restrict__ wob) {
  __shared__ float t[64][65];
  const int blk = blockIdx.x;
  const int tid = threadIdx.x;

  if (blk < 8192) {
    const float* in = (blk < 4096) ? x : enc;
    u16* out = (blk < 4096) ? xb : eb;
    size_t i = (size_t)(blk & 4095) * 256 + tid;
    const float4* p = (const float4*)in + i * 2;
    float4 a = p[0], b = p[1];
    us8 o;
    o[0] = f2bf(a.x); o[1] = f2bf(a.y); o[2] = f2bf(a.z); o[3] = f2bf(a.w);
    o[4] = f2bf(b.x); o[5] = f2bf(b.y); o[6] = f2bf(b.z); o[7] = f2bf(b.w);
    *(us8*)(out + i * 8) = o;
    return;
  }

  if (blk < 8960) {
    int r = blk - 8192;
    int z = r >> 8;
    const float* W = (z == 0) ? Wq : (z == 1) ? Wk : Wv;
    u16* o = (z == 0) ? wqb : (z == 1) ? wkb : wvb;
    const int h = (r & 255) >> 4, d0 = (r & 15) * 64;
    const float* Wb = W + ((size_t)h << 16) + (size_t)d0 * 64;
#pragma unroll
    for (int i = 0; i < 4; ++i) {
      int idx = tid + i * 256;
      int dl = idx >> 4, e4 = (idx & 15) << 2;
      float4 v = *(const float4*)(Wb + dl * 64 + e4);
      t[dl][e4 + 0] = v.x; t[dl][e4 + 1] = v.y; t[dl][e4 + 2] = v.z; t[dl][e4 + 3] = v.w;
    }
    __syncthreads();
#pragma unroll
    for (int i = 0; i < 2; ++i) {
      int idx = tid + i * 256;
      int e = idx >> 3, dc = (idx & 7) * 8;
      us8 w;
#pragma unroll
      for (int j = 0; j < 8; ++j) w[j] = f2bf(t[dc + j][e]);
      *(us8*)(o + ((size_t)(h * 64 + e)) * 1024 + d0 + dc) = w;
    }
    return;
  }

  {
    int r = blk - 8960;
    const int k0 = (r & 15) * 64, n0 = (r >> 4) * 64;
    const float* Wb = Wo + (size_t)k0 * 1024 + n0;
#pragma unroll
    for (int i = 0; i < 4; ++i) {
      int idx = tid + i * 256;
      int kl = idx >> 4, n4 = (idx & 15) << 2;
      float4 v = *(const float4*)(Wb + (size_t)kl * 1024 + n4);
      t[kl][n4 + 0] = v.x; t[kl][n4 + 1] = v.y; t[kl][n4 + 2] = v.z; t[kl][n4 + 3] = v.w;
    }
    __syncthreads();
#pragma unroll
    for (int i = 0; i < 2; ++i) {
      int idx = tid + i * 256;
      int n = idx >> 3, kc = (idx & 7) * 8;
      us8 w;
#pragma unroll
      for (int j = 0; j < 8; ++j) w[j] = f2bf(t[kc + j][n]);
      *(us8*)(wob + ((size_t)(n0 + n)) * 1024 + k0 + kc) = w;
    }
  }
}

// ---------------- shared GEMM mainloop (128x128 tile, BK=32, 2-deep vmcnt(4)) ----
__device__ __forceinline__ void gemm_core(const char* Ac, const char* Bc, int K,
                                          int m0, int n0, int tid,
                                          char* As0, char* As1, char* Bs0, char* Bs1,
                                          f32x4 (&acc)[4][4]) {
  const int wave = tid >> 6, lane = tid & 63;
  const int lo = lane & 15, hi = lane >> 4;
  const int wr = wave >> 1, wc = wave & 1;
  const int o0 = wave * 1024 + lane * 16;
  const int r0 = o0 >> 6, cb0 = o0 & 63;
  const int o1 = o0 + 4096;
  const int r1 = o1 >> 6, cb1 = o1 & 63;
  const size_t ksz = (size_t)K * 2;

  auto STAGE = [&](int t) {
    const size_t kb = (size_t)t * 64;
    char* Ad = (t & 1) ? As1 : As0;
    char* Bd = (t & 1) ? Bs1 : Bs0;
    gload_lds16(Ac + (size_t)(m0 + r0) * ksz + kb + cb0, Ad + o0);
    gload_lds16(Ac + (size_t)(m0 + r1) * ksz + kb + cb1, Ad + o1);
    gload_lds16(Bc + (size_t)(n0 + r0) * ksz + kb + cb0, Bd + o0);
    gload_lds16(Bc + (size_t)(n0 + r1) * ksz + kb + cb1, Bd + o1);
  };

  const int NK = K >> 5;
  STAGE(0);
  STAGE(1);

  for (int kk = 0; kk < NK; ++kk) {
    if (kk < NK - 1) {
      asm volatile("s_waitcnt vmcnt(4)" ::: "memory");
    } else {
      asm volatile("s_waitcnt vmcnt(0)" ::: "memory");
    }
    __builtin_amdgcn_s_barrier();
    __builtin_amdgcn_sched_barrier(0);
    const u16* Asb = (const u16*)((kk & 1) ? As1 : As0);
    const u16* Bsb = (const u16*)((kk & 1) ? Bs1 : Bs0);
    bf16x8 af[4], bfr[4];
#pragma unroll
    for (int i = 0; i < 4; ++i) {
      af[i]  = *(const bf16x8*)(Asb + (wr * 64 + i * 16 + lo) * 32 + hi * 8);
      bfr[i] = *(const bf16x8*)(Bsb + (wc * 64 + i * 16 + lo) * 32 + hi * 8);
    }
    asm volatile("s_waitcnt lgkmcnt(0)" ::: "memory");
    __builtin_amdgcn_sched_barrier(0);
    __builtin_amdgcn_s_barrier();
    if (kk + 2 < NK) STAGE(kk + 2);
    __builtin_amdgcn_s_setprio(1);
#pragma unroll
    for (int am = 0; am < 4; ++am)
#pragma unroll
      for (int bn = 0; bn < 4; ++bn)
        acc[am][bn] = __builtin_amdgcn_mfma_f32_16x16x32_bf16(af[am], bfr[bn], acc[am][bn], 0, 0, 0);
    __builtin_amdgcn_s_setprio(0);
  }
}

// ---------------- fused Q + KV projections (XCD-clustered block order) ----------
__global__ __launch_bounds__(256) void qkv_proj_k(
    const u16* __restrict__ xb, const u16* __restrict__ eb,
    const u16* __restrict__ wqb, const u16* __restrict__ wkvb,
    const float* __restrict__ bq, const float* __restrict__ bk_,
    const float* __restrict__ bv_,
    u16* __restrict__ Qg, u16* __restrict__ Kg, u16* __restrict__ Vt, float scale) {
  __shared__ __attribute__((aligned(16))) char As[2][8192];
  __shared__ __attribute__((aligned(16))) char Bs[2][8192];
  // T1 XCD swizzle (bijective: 1536 = 8*192): XCD x runs a contiguous logical
  // chunk of 192 blocks -> blocks sharing an A-panel get L2 affinity.
  const int blk = ((int)blockIdx.x % 8) * 192 + (int)blockIdx.x / 8;
  const int tid = threadIdx.x;
  const int wave = tid >> 6, lane = tid & 63;
  const int lo = lane & 15, hi = lane >> 4;
  const int wr = wave >> 1, wc = wave & 1;

  f32x4 acc[4][4] = {};

  if (blk < 512) {
    const int n0 = (blk & 7) * 128, m0 = (blk >> 3) * 128;
    gemm_core((const char*)xb, (const char*)wqb, 1024, m0, n0, tid,
              As[0], As[1], Bs[0], Bs[1], acc);
#pragma unroll
    for (int bn = 0; bn < 4; ++bn) {
      int col = n0 + wc * 64 + bn * 16 + lo;
      float bb = bq[col];
      int hh = col >> 6, e = col & 63;
#pragma unroll
      for (int am = 0; am < 4; ++am) {
#pragma unroll
        for (int r = 0; r < 4; ++r) {
          int row = m0 + wr * 64 + am * 16 + hi * 4 + r;
          int b = row >> 11, s = row & 2047;
          Qg[(((size_t)(b * 16 + hh) * 2048 + s) << 6) + e] = f2bf((acc[am][bn][r] + bb) * scale);
        }
      }
    }
  } else {
    const int r_ = blk - 512;
    const int n0 = (r_ & 15) * 128, m0 = (r_ >> 4) * 128;
    gemm_core((const char*)eb, (const char*)wkvb, 1024, m0, n0, tid,
              As[0], As[1], Bs[0], Bs[1], acc);
    const bool isV = (n0 + wc * 64) >= 1024;  // wave-uniform
    if (!isV) {
#pragma unroll
      for (int bn = 0; bn < 4; ++bn) {
        int col = n0 + wc * 64 + bn * 16 + lo;
        float bb = bk_[col];
        int hh = col >> 6, e = col & 63;
#pragma unroll
        for (int am = 0; am < 4; ++am) {
#pragma unroll
          for (int r = 0; r < 4; ++r) {
            int row = m0 + wr * 64 + am * 16 + hi * 4 + r;
            int b = row >> 11, s = row & 2047;
            s = (s & ~12) | ((s & 4) << 1) | ((s & 8) >> 1);
            Kg[(((size_t)(b * 16 + hh) * 2048 + s) << 6) + e] = f2bf(acc[am][bn][r] + bb);
          }
        }
      }
    } else {
#pragma unroll
      for (int bn = 0; bn < 4; ++bn) {
        int c = (n0 + wc * 64 + bn * 16 + lo) - 1024;
        float bb = bv_[c];
        int hh = c >> 6, e = c & 63;
#pragma unroll
        for (int am = 0; am < 4; ++am) {
          int row = m0 + wr * 64 + am * 16 + hi * 4;
          int b = row >> 11, s = row & 2047;
          uint2 wv;
          wv.x = cvtpk(acc[am][bn][0] + bb, acc[am][bn][1] + bb);
          wv.y = cvtpk(acc[am][bn][2] + bb, acc[am][bn][3] + bb);
          *(uint2*)(Vt + (((size_t)(b * 16 + hh) * 64 + e) * 2048 + s)) = wv;
        }
      }
    }
  }
}

// ---------------- output projection ----------------
__global__ __launch_bounds__(256) void out_proj_k(const u16* __restrict__ A,
                                                  const u16* __restrict__ B,
                                                  const float* __restrict__ bias,
                                                  float* __restrict__ C, int M, int N, int K) {
  __shared__ __attribute__((aligned(16))) char As[2][8192];
  __shared__ __attribute__((aligned(16))) char Bs[2][8192];
  const int tid = threadIdx.x;
  const int wave = tid >> 6, lane = tid & 63;
  const int lo = lane & 15, hi = lane >> 4;
  const int wr = wave >> 1, wc = wave & 1;
  const int n0 = blockIdx.x * 128, m0 = blockIdx.y * 128;

  f32x4 acc[4][4] = {};
  gemm_core((const char*)A, (const char*)B, K, m0, n0, tid,
            As[0], As[1], Bs[0], Bs[1], acc);

#pragma unroll
  for (int bn = 0; bn < 4; ++bn) {
    int col = n0 + wc * 64 + bn * 16 + lo;
    float bb = bias[col];
#pragma unroll
    for (int am = 0; am < 4; ++am) {
#pragma unroll
      for (int r = 0; r < 4; ++r) {
        int row = m0 + wr * 64 + am * 16 + hi * 4 + r;
        C[(size_t)row * N + col] = acc[am][bn][r] + bb;
      }
    }
  }
}

// ---------------- flash attention (R4-proven body, VALU row-sum) ----------------
// Q pre-scaled by log2(e)/8 in its projection. exp2 accumulated raw; normalize at end.
__global__ __launch_bounds__(256, 4) void attn_k(const u16* __restrict__ Qg,
                                                 const u16* __restrict__ Kg,
                                                 const u16* __restrict__ Vtg,
                                                 u16* __restrict__ Hd) {
  const int W = blockIdx.x;
  const int bid = (W >> 7) * 128 + (W & 7) * 16 + ((W >> 3) & 15);
  const int bh = bid >> 4;
  const int q0 = (bid & 15) * 128;
  const int tid = threadIdx.x;
  const int w = tid >> 6, lane = tid & 63;
  const int q31 = lane & 31, g = lane >> 5;

  __shared__ __attribute__((aligned(16))) char LB[2][16384];  // [K 8KB | V 8KB] x2

  bf16x8 qf0, qf1, qf2, qf3;
  {
    const char* Qrow = (const char*)(Qg + ((size_t)bh * 2048 + q0 + w * 32 + q31) * 64) + g * 16;
    qf0 = *(const bf16x8*)(Qrow);
    qf1 = *(const bf16x8*)(Qrow + 32);
    qf2 = *(const bf16x8*)(Qrow + 64);
    qf3 = *(const bf16x8*)(Qrow + 96);
  }

  f32x16 acc0 = {}, acc1 = {};
  float lrun = 0.f;

  const int lrow = lane >> 3;
  const int scol = ((lane & 7) ^ lrow) << 4;
  const char* kp = (const char*)Kg + (size_t)bh * 262144 + (size_t)(w * 16 + lrow) * 128 + scol;
  const char* vp = (const char*)Vtg + (size_t)bh * 262144 + (size_t)(w * 16 + lrow) * 4096 + scol;

  auto STAGE = [&](int c) {
    char* kb = &LB[c][0] + w * 2048;
    char* vb = kb + 8192;
    gload_lds16(kp, kb);
    gload_lds16(kp + 1024, kb + 1024);
    gload_lds16(vp, vb);
    gload_lds16(vp + 32768, vb + 1024);
    kp += 8192;
    vp += 128;
  };

  STAGE(0);

  const int swz = (q31 & 7) << 4;
  const int krow = q31 * 128;
  const int ko0 = (g * 16) ^ swz;
  const int ko1 = (32 + g * 16) ^ swz;
  const int ko2 = (64 + g * 16) ^ swz;
  const int ko3 = (96 + g * 16) ^ swz;

  int cur = 0;
  for (int t = 0; t < 32; ++t) {
    asm volatile("s_waitcnt vmcnt(0)" ::: "memory");
    __builtin_amdgcn_s_barrier();
    asm volatile("" ::: "memory");
    if (t < 31) STAGE(cur ^ 1);

    const char* Kc = &LB[cur][0];
    const char* Vc = Kc + 8192;

    f32x16 p0 = {}, p1 = {};
    __builtin_amdgcn_s_setprio(1);
    {
      bf16x8 kf;
      kf = *(const bf16x8*)(Kc + krow + ko0);
      p0 = __builtin_amdgcn_mfma_f32_32x32x16_bf16(kf, qf0, p0, 0, 0, 0);
      kf = *(const bf16x8*)(Kc + 4096 + krow + ko0);
      p1 = __builtin_amdgcn_mfma_f32_32x32x16_bf16(kf, qf0, p1, 0, 0, 0);
      kf = *(const bf16x8*)(Kc + krow + ko1);
      p0 = __builtin_amdgcn_mfma_f32_32x32x16_bf16(kf, qf1, p0, 0, 0, 0);
      kf = *(const bf16x8*)(Kc + 4096 + krow + ko1);
      p1 = __builtin_amdgcn_mfma_f32_32x32x16_bf16(kf, qf1, p1, 0, 0, 0);
      kf = *(const bf16x8*)(Kc + krow + ko2);
      p0 = __builtin_amdgcn_mfma_f32_32x32x16_bf16(kf, qf2, p0, 0, 0, 0);
      kf = *(const bf16x8*)(Kc + 4096 + krow + ko2);
      p1 = __builtin_amdgcn_mfma_f32_32x32x16_bf16(kf, qf2, p1, 0, 0, 0);
      kf = *(const bf16x8*)(Kc + krow + ko3);
      p0 = __builtin_amdgcn_mfma_f32_32x32x16_bf16(kf, qf3, p0, 0, 0, 0);
      kf = *(const bf16x8*)(Kc + 4096 + krow + ko3);
      p1 = __builtin_amdgcn_mfma_f32_32x32x16_bf16(kf, qf3, p1, 0, 0, 0);
    }
    __builtin_amdgcn_s_setprio(0);

#pragma unroll
    for (int i = 0; i < 16; ++i) p0[i] = __builtin_amdgcn_exp2f(p0[i]);
#pragma unroll
    for (int i = 0; i < 16; ++i) p1[i] = __builtin_amdgcn_exp2f(p1[i]);

    float rs = vsum16(p0) + vsum16(p1);
    {
      float ra = rs, rb = rs;
      asm("v_permlane32_swap_b32 %0, %1" : "+v"(ra), "+v"(rb));
      rs += g ? ra : rb;
    }
    lrun += rs;

    union PU { uint32_t u[4]; bf16x8 v; } a0, a1, a2, a3;
    a0.u[0] = cvtpk(p0[0], p0[1]);   a0.u[1] = cvtpk(p0[2], p0[3]);
    a0.u[2] = cvtpk(p0[4], p0[5]);   a0.u[3] = cvtpk(p0[6], p0[7]);
    a1.u[0] = cvtpk(p0[8], p0[9]);   a1.u[1] = cvtpk(p0[10], p0[11]);
    a1.u[2] = cvtpk(p0[12], p0[13]); a1.u[3] = cvtpk(p0[14], p0[15]);
    a2.u[0] = cvtpk(p1[0], p1[1]);   a2.u[1] = cvtpk(p1[2], p1[3]);
    a2.u[2] = cvtpk(p1[4], p1[5]);   a2.u[3] = cvtpk(p1[6], p1[7]);
    a3.u[0] = cvtpk(p1[8], p1[9]);   a3.u[1] = cvtpk(p1[10], p1[11]);
    a3.u[2] = cvtpk(p1[12], p1[13]); a3.u[3] = cvtpk(p1[14], p1[15]);

    __builtin_amdgcn_s_setprio(1);
    {
      bf16x8 vf;
      vf = *(const bf16x8*)(Vc + krow + ko0);
      acc0 = __builtin_amdgcn_mfma_f32_32x32x16_bf16(a0.v, vf, acc0, 0, 0, 0);
      vf = *(const bf16x8*)(Vc + 4096 + krow + ko0);
      acc1 = __builtin_amdgcn_mfma_f32_32x32x16_bf16(a0.v, vf, acc1, 0, 0, 0);
      vf = *(const bf16x8*)(Vc + krow + ko1);
      acc0 = __builtin_amdgcn_mfma_f32_32x32x16_bf16(a1.v, vf, acc0, 0, 0, 0);
      vf = *(const bf16x8*)(Vc + 4096 + krow + ko1);
      acc1 = __builtin_amdgcn_mfma_f32_32x32x16_bf16(a1.v, vf, acc1, 0, 0, 0);
      vf = *(const bf16x8*)(Vc + krow + ko2);
      acc0 = __builtin_amdgcn_mfma_f32_32x32x16_bf16(a2.v, vf, acc0, 0, 0, 0);
      vf = *(const bf16x8*)(Vc + 4096 + krow + ko2);
      acc1 = __builtin_amdgcn_mfma_f32_32x32x16_bf16(a2.v, vf, acc1, 0, 0, 0);
      vf = *(const bf16x8*)(Vc + krow + ko3);
      acc0 = __builtin_amdgcn_mfma_f32_32x32x16_bf16(a3.v, vf, acc0, 0, 0, 0);
      vf = *(const bf16x8*)(Vc + 4096 + krow + ko3);
      acc1 = __builtin_amdgcn_mfma_f32_32x32x16_bf16(a3.v, vf, acc1, 0, 0, 0);
    }
    __builtin_amdgcn_s_setprio(0);

    cur ^= 1;
  }

  float linv = 1.f / lrun;
  const int b = bh >> 4, h = bh & 15;
  u16* Ho = Hd + ((size_t)b * 2048 + q0 + w * 32) * 1024 + h * 64;
#pragma unroll
  for (int r = 0; r < 16; ++r) {
    float iv = __shfl(linv, CROW(r, g));
    int q = CROW(r, g);
    u16* row = Ho + (size_t)q * 1024;
    row[q31]      = f2bf(acc0[r] * iv);
    row[32 + q31] = f2bf(acc1[r] * iv);
  }
}

// ---------------- launch ----------------

extern "C" void kernel_launch(void* const* d_in, const int* in_sizes, int n_in,
                              void* d_out, int out_size, void* d_ws, size_t ws_size,
                              hipStream_t stream) {
  const float* x   = (const float*)d_in[0];
  const float* enc = (const float*)d_in[1];
  const float* Wq  = (const float*)d_in[2];
  const float* bq  = (const float*)d_in[3];
  const float* Wk  = (const float*)d_in[4];
  const float* bk  = (const float*)d_in[5];
  const float* Wv  = (const float*)d_in[6];
  const float* bv  = (const float*)d_in[7];
  const float* Wo  = (const float*)d_in[8];
  const float* bo  = (const float*)d_in[9];
  float* out = (float*)d_out;
  char* ws = (char*)d_ws;

  const size_t SZ = 16u * 1024u * 1024u;
  u16* xb  = (u16*)(ws + 0 * SZ);  // also Hd (x dead after Q proj)
  u16* eb  = (u16*)(ws + 1 * SZ);
  u16* Qg  = (u16*)(ws + 2 * SZ);
  u16* Kg  = (u16*)(ws + 3 * SZ);
  u16* vtb = (u16*)(ws + 4 * SZ);  // Vt [B,H,64,S], written directly by KV gemm
  u16* wqb = (u16*)(ws + 5 * SZ + 0u * (2u << 20));
  u16* wkb = (u16*)(ws + 5 * SZ + 1u * (2u << 20));  // wkb+wvb contiguous [2048][1024]
  u16* wob = (u16*)(ws + 5 * SZ + 3u * (2u << 20));
  u16* hd  = xb;

  const float cs = 0.18033688011112042f;  // log2(e)/8, folded into Q projection

  cvt_all_k<<<9216, 256, 0, stream>>>(x, enc, Wq, Wk, Wv, Wo, xb, eb, wqb, wkb,
                                      (u16*)(ws + 5 * SZ + 2u * (2u << 20)), wob);

  qkv_proj_k<<<1536, 256, 0, stream>>>(xb, eb, wqb, wkb, bq, bk, bv, Qg, Kg, vtb, cs);

  attn_k<<<1024, 256, 0, stream>>>(Qg, Kg, vtb, hd);

  out_proj_k<<<dim3(8, 64), 256, 0, stream>>>(hd, wob, bo, out, 8192, 1024, 1024);
}

// Round 12
// 190.316 us; speedup vs baseline: 1.1015x; 1.0127x over previous
//
#include <hip/hip_runtime.h>
#include <hip/hip_bf16.h>
#include <stdint.h>

typedef unsigned short u16;
typedef __bf16 bf16x8 __attribute__((ext_vector_type(8)));
typedef float f32x4 __attribute__((ext_vector_type(4)));
typedef float f32x16 __attribute__((ext_vector_type(16)));
typedef unsigned short us8 __attribute__((ext_vector_type(8)));

__device__ __forceinline__ u16 f2bf(float f) {
  union { float f; uint32_t u; } v; v.f = f;
  uint32_t u = v.u;
  return (u16)((u + 0x7FFFu + ((u >> 16) & 1u)) >> 16);
}

__device__ __forceinline__ uint32_t cvtpk(float a, float b) {
  uint32_t r;
  asm("v_cvt_pk_bf16_f32 %0, %1, %2" : "=v"(r) : "v"(a), "v"(b));
  return r;
}

__device__ __forceinline__ void gload_lds16(const void* g, void* l) {
  __builtin_amdgcn_global_load_lds(
      (const __attribute__((address_space(1))) void*)(uintptr_t)g,
      (__attribute__((address_space(3))) void*)(uint32_t)(uintptr_t)l,
      16, 0, 0);
}

__device__ __forceinline__ float vsum16(f32x16 v) {
  float a = (v[0] + v[1]) + (v[2] + v[3]);
  float b = (v[4] + v[5]) + (v[6] + v[7]);
  float c = (v[8] + v[9]) + (v[10] + v[11]);
  float d = (v[12] + v[13]) + (v[14] + v[15]);
  return (a + b) + (c + d);
}

#define CROW(r, g) (((r) & 3) + 8 * ((r) >> 2) + 4 * (g))

// ---------------- merged conversions ----------------
__global__ __launch_bounds__(256) void cvt_all_k(
    const float* __restrict__ x, const float* __restrict__ enc,
    const float* __restrict__ Wq, const float* __restrict__ Wk,
    const float* __restrict__ Wv, const float* __restrict__ Wo,
    u16* __restrict__ xb, u16* __restrict__ eb,
    u16* __restrict__ wqb, u16* __restrict__ wkb,
    u16* __restrict__ wvb, u16* __restrict__ wob) {
  __shared__ float t[64][65];
  const int blk = blockIdx.x;
  const int tid = threadIdx.x;

  if (blk < 8192) {
    const float* in = (blk < 4096) ? x : enc;
    u16* out = (blk < 4096) ? xb : eb;
    size_t i = (size_t)(blk & 4095) * 256 + tid;
    const float4* p = (const float4*)in + i * 2;
    float4 a = p[0], b = p[1];
    us8 o;
    o[0] = f2bf(a.x); o[1] = f2bf(a.y); o[2] = f2bf(a.z); o[3] = f2bf(a.w);
    o[4] = f2bf(b.x); o[5] = f2bf(b.y); o[6] = f2bf(b.z); o[7] = f2bf(b.w);
    *(us8*)(out + i * 8) = o;
    return;
  }

  if (blk < 8960) {
    int r = blk - 8192;
    int z = r >> 8;
    const float* W = (z == 0) ? Wq : (z == 1) ? Wk : Wv;
    u16* o = (z == 0) ? wqb : (z == 1) ? wkb : wvb;
    const int h = (r & 255) >> 4, d0 = (r & 15) * 64;
    const float* Wb = W + ((size_t)h << 16) + (size_t)d0 * 64;
#pragma unroll
    for (int i = 0; i < 4; ++i) {
      int idx = tid + i * 256;
      int dl = idx >> 4, e4 = (idx & 15) << 2;
      float4 v = *(const float4*)(Wb + dl * 64 + e4);
      t[dl][e4 + 0] = v.x; t[dl][e4 + 1] = v.y; t[dl][e4 + 2] = v.z; t[dl][e4 + 3] = v.w;
    }
    __syncthreads();
#pragma unroll
    for (int i = 0; i < 2; ++i) {
      int idx = tid + i * 256;
      int e = idx >> 3, dc = (idx & 7) * 8;
      us8 w;
#pragma unroll
      for (int j = 0; j < 8; ++j) w[j] = f2bf(t[dc + j][e]);
      *(us8*)(o + ((size_t)(h * 64 + e)) * 1024 + d0 + dc) = w;
    }
    return;
  }

  {
    int r = blk - 8960;
    const int k0 = (r & 15) * 64, n0 = (r >> 4) * 64;
    const float* Wb = Wo + (size_t)k0 * 1024 + n0;
#pragma unroll
    for (int i = 0; i < 4; ++i) {
      int idx = tid + i * 256;
      int kl = idx >> 4, n4 = (idx & 15) << 2;
      float4 v = *(const float4*)(Wb + (size_t)kl * 1024 + n4);
      t[kl][n4 + 0] = v.x; t[kl][n4 + 1] = v.y; t[kl][n4 + 2] = v.z; t[kl][n4 + 3] = v.w;
    }
    __syncthreads();
#pragma unroll
    for (int i = 0; i < 2; ++i) {
      int idx = tid + i * 256;
      int n = idx >> 3, kc = (idx & 7) * 8;
      us8 w;
#pragma unroll
      for (int j = 0; j < 8; ++j) w[j] = f2bf(t[kc + j][n]);
      *(us8*)(wob + ((size_t)(n0 + n)) * 1024 + k0 + kc) = w;
    }
  }
}

// ---------------- shared GEMM mainloop (128x128 tile, BK=32, 2-deep vmcnt(4)) ----
__device__ __forceinline__ void gemm_core(const char* Ac, const char* Bc, int K,
                                          int m0, int n0, int tid,
                                          char* As0, char* As1, char* Bs0, char* Bs1,
                                          f32x4 (&acc)[4][4]) {
  const int wave = tid >> 6, lane = tid & 63;
  const int lo = lane & 15, hi = lane >> 4;
  const int wr = wave >> 1, wc = wave & 1;
  const int o0 = wave * 1024 + lane * 16;
  const int r0 = o0 >> 6, cb0 = o0 & 63;
  const int o1 = o0 + 4096;
  const int r1 = o1 >> 6, cb1 = o1 & 63;
  const size_t ksz = (size_t)K * 2;

  auto STAGE = [&](int t) {
    const size_t kb = (size_t)t * 64;
    char* Ad = (t & 1) ? As1 : As0;
    char* Bd = (t & 1) ? Bs1 : Bs0;
    gload_lds16(Ac + (size_t)(m0 + r0) * ksz + kb + cb0, Ad + o0);
    gload_lds16(Ac + (size_t)(m0 + r1) * ksz + kb + cb1, Ad + o1);
    gload_lds16(Bc + (size_t)(n0 + r0) * ksz + kb + cb0, Bd + o0);
    gload_lds16(Bc + (size_t)(n0 + r1) * ksz + kb + cb1, Bd + o1);
  };

  const int NK = K >> 5;
  STAGE(0);
  STAGE(1);

  for (int kk = 0; kk < NK; ++kk) {
    if (kk < NK - 1) {
      asm volatile("s_waitcnt vmcnt(4)" ::: "memory");
    } else {
      asm volatile("s_waitcnt vmcnt(0)" ::: "memory");
    }
    __builtin_amdgcn_s_barrier();
    __builtin_amdgcn_sched_barrier(0);
    const u16* Asb = (const u16*)((kk & 1) ? As1 : As0);
    const u16* Bsb = (const u16*)((kk & 1) ? Bs1 : Bs0);
    bf16x8 af[4], bfr[4];
#pragma unroll
    for (int i = 0; i < 4; ++i) {
      af[i]  = *(const bf16x8*)(Asb + (wr * 64 + i * 16 + lo) * 32 + hi * 8);
      bfr[i] = *(const bf16x8*)(Bsb + (wc * 64 + i * 16 + lo) * 32 + hi * 8);
    }
    asm volatile("s_waitcnt lgkmcnt(0)" ::: "memory");
    __builtin_amdgcn_sched_barrier(0);
    __builtin_amdgcn_s_barrier();
    if (kk + 2 < NK) STAGE(kk + 2);
    __builtin_amdgcn_s_setprio(1);
#pragma unroll
    for (int am = 0; am < 4; ++am)
#pragma unroll
      for (int bn = 0; bn < 4; ++bn)
        acc[am][bn] = __builtin_amdgcn_mfma_f32_16x16x32_bf16(af[am], bfr[bn], acc[am][bn], 0, 0, 0);
    __builtin_amdgcn_s_setprio(0);
  }
}

// ---------------- fused Q + KV projections (XCD-clustered block order) ----------
__global__ __launch_bounds__(256) void qkv_proj_k(
    const u16* __restrict__ xb, const u16* __restrict__ eb,
    const u16* __restrict__ wqb, const u16* __restrict__ wkvb,
    const float* __restrict__ bq, const float* __restrict__ bk_,
    const float* __restrict__ bv_,
    u16* __restrict__ Qg, u16* __restrict__ Kg, u16* __restrict__ Vt, float scale) {
  __shared__ __attribute__((aligned(16))) char As[2][8192];
  __shared__ __attribute__((aligned(16))) char Bs[2][8192];
  // T1 XCD swizzle (bijective: 1536 = 8*192)
  const int blk = ((int)blockIdx.x % 8) * 192 + (int)blockIdx.x / 8;
  const int tid = threadIdx.x;
  const int wave = tid >> 6, lane = tid & 63;
  const int lo = lane & 15, hi = lane >> 4;
  const int wr = wave >> 1, wc = wave & 1;

  f32x4 acc[4][4] = {};

  if (blk < 512) {
    const int n0 = (blk & 7) * 128, m0 = (blk >> 3) * 128;
    gemm_core((const char*)xb, (const char*)wqb, 1024, m0, n0, tid,
              As[0], As[1], Bs[0], Bs[1], acc);
#pragma unroll
    for (int bn = 0; bn < 4; ++bn) {
      int col = n0 + wc * 64 + bn * 16 + lo;
      float bb = bq[col];
      int hh = col >> 6, e = col & 63;
#pragma unroll
      for (int am = 0; am < 4; ++am) {
#pragma unroll
        for (int r = 0; r < 4; ++r) {
          int row = m0 + wr * 64 + am * 16 + hi * 4 + r;
          int b = row >> 11, s = row & 2047;
          Qg[(((size_t)(b * 16 + hh) * 2048 + s) << 6) + e] = f2bf((acc[am][bn][r] + bb) * scale);
        }
      }
    }
  } else {
    const int r_ = blk - 512;
    const int n0 = (r_ & 15) * 128, m0 = (r_ >> 4) * 128;
    gemm_core((const char*)eb, (const char*)wkvb, 1024, m0, n0, tid,
              As[0], As[1], Bs[0], Bs[1], acc);
    const bool isV = (n0 + wc * 64) >= 1024;  // wave-uniform
    if (!isV) {
#pragma unroll
      for (int bn = 0; bn < 4; ++bn) {
        int col = n0 + wc * 64 + bn * 16 + lo;
        float bb = bk_[col];
        int hh = col >> 6, e = col & 63;
#pragma unroll
        for (int am = 0; am < 4; ++am) {
#pragma unroll
          for (int r = 0; r < 4; ++r) {
            int row = m0 + wr * 64 + am * 16 + hi * 4 + r;
            int b = row >> 11, s = row & 2047;
            s = (s & ~12) | ((s & 4) << 1) | ((s & 8) >> 1);
            Kg[(((size_t)(b * 16 + hh) * 2048 + s) << 6) + e] = f2bf(acc[am][bn][r] + bb);
          }
        }
      }
    } else {
#pragma unroll
      for (int bn = 0; bn < 4; ++bn) {
        int c = (n0 + wc * 64 + bn * 16 + lo) - 1024;
        float bb = bv_[c];
        int hh = c >> 6, e = c & 63;
#pragma unroll
        for (int am = 0; am < 4; ++am) {
          int row = m0 + wr * 64 + am * 16 + hi * 4;
          int b = row >> 11, s = row & 2047;
          uint2 wv;
          wv.x = cvtpk(acc[am][bn][0] + bb, acc[am][bn][1] + bb);
          wv.y = cvtpk(acc[am][bn][2] + bb, acc[am][bn][3] + bb);
          *(uint2*)(Vt + (((size_t)(b * 16 + hh) * 64 + e) * 2048 + s)) = wv;
        }
      }
    }
  }
}

// ---------------- output projection (XCD-clustered block order) ----------------
// grid 512 linear; bijective T1 swizzle (512 = 8*64): XCD x covers m-panels
// [8x, 8x+8) across all n-tiles -> hd A-panels L2-resident per XCD.
__global__ __launch_bounds__(256) void out_proj_k(const u16* __restrict__ A,
                                                  const u16* __restrict__ B,
                                                  const float* __restrict__ bias,
                                                  float* __restrict__ C, int M, int N, int K) {
  __shared__ __attribute__((aligned(16))) char As[2][8192];
  __shared__ __attribute__((aligned(16))) char Bs[2][8192];
  const int blk = ((int)blockIdx.x % 8) * 64 + (int)blockIdx.x / 8;
  const int tid = threadIdx.x;
  const int wave = tid >> 6, lane = tid & 63;
  const int lo = lane & 15, hi = lane >> 4;
  const int wr = wave >> 1, wc = wave & 1;
  const int n0 = (blk & 7) * 128, m0 = (blk >> 3) * 128;

  f32x4 acc[4][4] = {};
  gemm_core((const char*)A, (const char*)B, K, m0, n0, tid,
            As[0], As[1], Bs[0], Bs[1], acc);

#pragma unroll
  for (int bn = 0; bn < 4; ++bn) {
    int col = n0 + wc * 64 + bn * 16 + lo;
    float bb = bias[col];
#pragma unroll
    for (int am = 0; am < 4; ++am) {
#pragma unroll
      for (int r = 0; r < 4; ++r) {
        int row = m0 + wr * 64 + am * 16 + hi * 4 + r;
        C[(size_t)row * N + col] = acc[am][bn][r] + bb;
      }
    }
  }
}

// ---------------- flash attention (R4-proven body, VALU row-sum) ----------------
// Q pre-scaled by log2(e)/8 in its projection. exp2 accumulated raw; normalize at end.
__global__ __launch_bounds__(256, 4) void attn_k(const u16* __restrict__ Qg,
                                                 const u16* __restrict__ Kg,
                                                 const u16* __restrict__ Vtg,
                                                 u16* __restrict__ Hd) {
  const int W = blockIdx.x;
  const int bid = (W >> 7) * 128 + (W & 7) * 16 + ((W >> 3) & 15);
  const int bh = bid >> 4;
  const int q0 = (bid & 15) * 128;
  const int tid = threadIdx.x;
  const int w = tid >> 6, lane = tid & 63;
  const int q31 = lane & 31, g = lane >> 5;

  __shared__ __attribute__((aligned(16))) char LB[2][16384];  // [K 8KB | V 8KB] x2

  bf16x8 qf0, qf1, qf2, qf3;
  {
    const char* Qrow = (const char*)(Qg + ((size_t)bh * 2048 + q0 + w * 32 + q31) * 64) + g * 16;
    qf0 = *(const bf16x8*)(Qrow);
    qf1 = *(const bf16x8*)(Qrow + 32);
    qf2 = *(const bf16x8*)(Qrow + 64);
    qf3 = *(const bf16x8*)(Qrow + 96);
  }

  f32x16 acc0 = {}, acc1 = {};
  float lrun = 0.f;

  const int lrow = lane >> 3;
  const int scol = ((lane & 7) ^ lrow) << 4;
  const char* kp = (const char*)Kg + (size_t)bh * 262144 + (size_t)(w * 16 + lrow) * 128 + scol;
  const char* vp = (const char*)Vtg + (size_t)bh * 262144 + (size_t)(w * 16 + lrow) * 4096 + scol;

  auto STAGE = [&](int c) {
    char* kb = &LB[c][0] + w * 2048;
    char* vb = kb + 8192;
    gload_lds16(kp, kb);
    gload_lds16(kp + 1024, kb + 1024);
    gload_lds16(vp, vb);
    gload_lds16(vp + 32768, vb + 1024);
    kp += 8192;
    vp += 128;
  };

  STAGE(0);

  const int swz = (q31 & 7) << 4;
  const int krow = q31 * 128;
  const int ko0 = (g * 16) ^ swz;
  const int ko1 = (32 + g * 16) ^ swz;
  const int ko2 = (64 + g * 16) ^ swz;
  const int ko3 = (96 + g * 16) ^ swz;

  int cur = 0;
  for (int t = 0; t < 32; ++t) {
    asm volatile("s_waitcnt vmcnt(0)" ::: "memory");
    __builtin_amdgcn_s_barrier();
    asm volatile("" ::: "memory");
    if (t < 31) STAGE(cur ^ 1);

    const char* Kc = &LB[cur][0];
    const char* Vc = Kc + 8192;

    f32x16 p0 = {}, p1 = {};
    __builtin_amdgcn_s_setprio(1);
    {
      bf16x8 kf;
      kf = *(const bf16x8*)(Kc + krow + ko0);
      p0 = __builtin_amdgcn_mfma_f32_32x32x16_bf16(kf, qf0, p0, 0, 0, 0);
      kf = *(const bf16x8*)(Kc + 4096 + krow + ko0);
      p1 = __builtin_amdgcn_mfma_f32_32x32x16_bf16(kf, qf0, p1, 0, 0, 0);
      kf = *(const bf16x8*)(Kc + krow + ko1);
      p0 = __builtin_amdgcn_mfma_f32_32x32x16_bf16(kf, qf1, p0, 0, 0, 0);
      kf = *(const bf16x8*)(Kc + 4096 + krow + ko1);
      p1 = __builtin_amdgcn_mfma_f32_32x32x16_bf16(kf, qf1, p1, 0, 0, 0);
      kf = *(const bf16x8*)(Kc + krow + ko2);
      p0 = __builtin_amdgcn_mfma_f32_32x32x16_bf16(kf, qf2, p0, 0, 0, 0);
      kf = *(const bf16x8*)(Kc + 4096 + krow + ko2);
      p1 = __builtin_amdgcn_mfma_f32_32x32x16_bf16(kf, qf2, p1, 0, 0, 0);
      kf = *(const bf16x8*)(Kc + krow + ko3);
      p0 = __builtin_amdgcn_mfma_f32_32x32x16_bf16(kf, qf3, p0, 0, 0, 0);
      kf = *(const bf16x8*)(Kc + 4096 + krow + ko3);
      p1 = __builtin_amdgcn_mfma_f32_32x32x16_bf16(kf, qf3, p1, 0, 0, 0);
    }
    __builtin_amdgcn_s_setprio(0);

#pragma unroll
    for (int i = 0; i < 16; ++i) p0[i] = __builtin_amdgcn_exp2f(p0[i]);
#pragma unroll
    for (int i = 0; i < 16; ++i) p1[i] = __builtin_amdgcn_exp2f(p1[i]);

    float rs = vsum16(p0) + vsum16(p1);
    {
      float ra = rs, rb = rs;
      asm("v_permlane32_swap_b32 %0, %1" : "+v"(ra), "+v"(rb));
      rs += g ? ra : rb;
    }
    lrun += rs;

    union PU { uint32_t u[4]; bf16x8 v; } a0, a1, a2, a3;
    a0.u[0] = cvtpk(p0[0], p0[1]);   a0.u[1] = cvtpk(p0[2], p0[3]);
    a0.u[2] = cvtpk(p0[4], p0[5]);   a0.u[3] = cvtpk(p0[6], p0[7]);
    a1.u[0] = cvtpk(p0[8], p0[9]);   a1.u[1] = cvtpk(p0[10], p0[11]);
    a1.u[2] = cvtpk(p0[12], p0[13]); a1.u[3] = cvtpk(p0[14], p0[15]);
    a2.u[0] = cvtpk(p1[0], p1[1]);   a2.u[1] = cvtpk(p1[2], p1[3]);
    a2.u[2] = cvtpk(p1[4], p1[5]);   a2.u[3] = cvtpk(p1[6], p1[7]);
    a3.u[0] = cvtpk(p1[8], p1[9]);   a3.u[1] = cvtpk(p1[10], p1[11]);
    a3.u[2] = cvtpk(p1[12], p1[13]); a3.u[3] = cvtpk(p1[14], p1[15]);

    __builtin_amdgcn_s_setprio(1);
    {
      bf16x8 vf;
      vf = *(const bf16x8*)(Vc + krow + ko0);
      acc0 = __builtin_amdgcn_mfma_f32_32x32x16_bf16(a0.v, vf, acc0, 0, 0, 0);
      vf = *(const bf16x8*)(Vc + 4096 + krow + ko0);
      acc1 = __builtin_amdgcn_mfma_f32_32x32x16_bf16(a0.v, vf, acc1, 0, 0, 0);
      vf = *(const bf16x8*)(Vc + krow + ko1);
      acc0 = __builtin_amdgcn_mfma_f32_32x32x16_bf16(a1.v, vf, acc0, 0, 0, 0);
      vf = *(const bf16x8*)(Vc + 4096 + krow + ko1);
      acc1 = __builtin_amdgcn_mfma_f32_32x32x16_bf16(a1.v, vf, acc1, 0, 0, 0);
      vf = *(const bf16x8*)(Vc + krow + ko2);
      acc0 = __builtin_amdgcn_mfma_f32_32x32x16_bf16(a2.v, vf, acc0, 0, 0, 0);
      vf = *(const bf16x8*)(Vc + 4096 + krow + ko2);
      acc1 = __builtin_amdgcn_mfma_f32_32x32x16_bf16(a2.v, vf, acc1, 0, 0, 0);
      vf = *(const bf16x8*)(Vc + krow + ko3);
      acc0 = __builtin_amdgcn_mfma_f32_32x32x16_bf16(a3.v, vf, acc0, 0, 0, 0);
      vf = *(const bf16x8*)(Vc + 4096 + krow + ko3);
      acc1 = __builtin_amdgcn_mfma_f32_32x32x16_bf16(a3.v, vf, acc1, 0, 0, 0);
    }
    __builtin_amdgcn_s_setprio(0);

    cur ^= 1;
  }

  float linv = 1.f / lrun;
  const int b = bh >> 4, h = bh & 15;
  u16* Ho = Hd + ((size_t)b * 2048 + q0 + w * 32) * 1024 + h * 64;
#pragma unroll
  for (int r = 0; r < 16; ++r) {
    float iv = __shfl(linv, CROW(r, g));
    int q = CROW(r, g);
    u16* row = Ho + (size_t)q * 1024;
    row[q31]      = f2bf(acc0[r] * iv);
    row[32 + q31] = f2bf(acc1[r] * iv);
  }
}

// ---------------- launch ----------------

extern "C" void kernel_launch(void* const* d_in, const int* in_sizes, int n_in,
                              void* d_out, int out_size, void* d_ws, size_t ws_size,
                              hipStream_t stream) {
  const float* x   = (const float*)d_in[0];
  const float* enc = (const float*)d_in[1];
  const float* Wq  = (const float*)d_in[2];
  const float* bq  = (const float*)d_in[3];
  const float* Wk  = (const float*)d_in[4];
  const float* bk  = (const float*)d_in[5];
  const float* Wv  = (const float*)d_in[6];
  const float* bv  = (const float*)d_in[7];
  const float* Wo  = (const float*)d_in[8];
  const float* bo  = (const float*)d_in[9];
  float* out = (float*)d_out;
  char* ws = (char*)d_ws;

  const size_t SZ = 16u * 1024u * 1024u;
  u16* xb  = (u16*)(ws + 0 * SZ);  // also Hd (x dead after Q proj)
  u16* eb  = (u16*)(ws + 1 * SZ);
  u16* Qg  = (u16*)(ws + 2 * SZ);
  u16* Kg  = (u16*)(ws + 3 * SZ);
  u16* vtb = (u16*)(ws + 4 * SZ);  // Vt [B,H,64,S], written directly by KV gemm
  u16* wqb = (u16*)(ws + 5 * SZ + 0u * (2u << 20));
  u16* wkb = (u16*)(ws + 5 * SZ + 1u * (2u << 20));  // wkb+wvb contiguous [2048][1024]
  u16* wob = (u16*)(ws + 5 * SZ + 3u * (2u << 20));
  u16* hd  = xb;

  const float cs = 0.18033688011112042f;  // log2(e)/8, folded into Q projection

  cvt_all_k<<<9216, 256, 0, stream>>>(x, enc, Wq, Wk, Wv, Wo, xb, eb, wqb, wkb,
                                      (u16*)(ws + 5 * SZ + 2u * (2u << 20)), wob);

  qkv_proj_k<<<1536, 256, 0, stream>>>(xb, eb, wqb, wkb, bq, bk, bv, Qg, Kg, vtb, cs);

  attn_k<<<1024, 256, 0, stream>>>(Qg, Kg, vtb, hd);

  out_proj_k<<<512, 256, 0, stream>>>(hd, wob, bo, out, 8192, 1024, 1024);
}